// Round 16
// baseline (179.050 us; speedup 1.0000x reference)
//
#include <hip/hip_runtime.h>

#define NN 2048
#define DD 256
#define HH 4
#define ECAP 128
#define SCAP 64      // slots per half-row segment (mean 15.4, +12.5 sigma)

typedef unsigned short ushort_t;
typedef __attribute__((ext_vector_type(4))) unsigned short us4;
typedef __attribute__((ext_vector_type(8))) unsigned short us8;
typedef __attribute__((ext_vector_type(8))) short s8;
typedef __attribute__((ext_vector_type(4))) float f4;

__device__ __forceinline__ ushort_t f2b(float f) {   // fp32 -> bf16 bits, RNE
    unsigned int u = __float_as_uint(f);
    return (ushort_t)((u + 0x7fffu + ((u >> 16) & 1u)) >> 16);
}
__device__ __forceinline__ float b2f(ushort_t b) {
    return __uint_as_float(((unsigned int)b) << 16);
}
__device__ __forceinline__ void gl_lds16(const void* g, void* l) {
    __builtin_amdgcn_global_load_lds(
        (const __attribute__((address_space(1))) void*)g,
        (__attribute__((address_space(3))) void*)l, 16, 0, 0);
}

// ---------------------------------------------------------------------------
// bf16 gemm core (gl_lds staging, XOR-swizzled [64][64]) — used by gemm2.
// ---------------------------------------------------------------------------
__device__ __forceinline__ void gemm_core(
    const ushort_t* __restrict__ A, int lda, const ushort_t* __restrict__ B, int ldb,
    int r0, int c0, int K, ushort_t (*as)[64], ushort_t (*bs)[64], f4 acc[2][2])
{
    const int t = threadIdx.x;
    const int wave = t >> 6, lane = t & 63;
    const int wm = (wave & 1) * 32, wn = (wave >> 1) * 32;
    const int fm = lane & 15, fq = lane >> 4;

    const int m0q0 = wave * 16 + (lane >> 3);
    const int m0q1 = m0q0 + 8;
    const int cs0 = ((lane & 7) ^ (m0q0 & 7)) * 8;
    const int cs1 = ((lane & 7) ^ (m0q1 & 7)) * 8;
    const ushort_t* ga0 = A + (size_t)(r0 + m0q0) * lda + cs0;
    const ushort_t* ga1 = A + (size_t)(r0 + m0q1) * lda + cs1;
    const ushort_t* gb0 = B + (size_t)(c0 + m0q0) * ldb + cs0;
    const ushort_t* gb1 = B + (size_t)(c0 + m0q1) * ldb + cs1;
    ushort_t* la0 = &as[wave * 16][0];
    ushort_t* la1 = &as[wave * 16 + 8][0];
    ushort_t* lb0 = &bs[wave * 16][0];
    ushort_t* lb1 = &bs[wave * 16 + 8][0];
    const int ra0 = wm + fm, ra1 = wm + 16 + fm;
    const int rb0 = wn + fm, rb1 = wn + 16 + fm;

    for (int k0 = 0; k0 < K; k0 += 64) {
        __syncthreads();
        gl_lds16(ga0 + k0, la0);
        gl_lds16(ga1 + k0, la1);
        gl_lds16(gb0 + k0, lb0);
        gl_lds16(gb1 + k0, lb1);
        __syncthreads();
        #pragma unroll
        for (int kk = 0; kk < 2; ++kk) {
            const int cc = kk * 4 + fq;
            const s8 a0 = *(const s8*)&as[ra0][(cc ^ (ra0 & 7)) * 8];
            const s8 a1 = *(const s8*)&as[ra1][(cc ^ (ra1 & 7)) * 8];
            const s8 b0 = *(const s8*)&bs[rb0][(cc ^ (rb0 & 7)) * 8];
            const s8 b1 = *(const s8*)&bs[rb1][(cc ^ (rb1 & 7)) * 8];
            acc[0][0] = __builtin_amdgcn_mfma_f32_16x16x32_bf16(a0, b0, acc[0][0], 0, 0, 0);
            acc[0][1] = __builtin_amdgcn_mfma_f32_16x16x32_bf16(a0, b1, acc[0][1], 0, 0, 0);
            acc[1][0] = __builtin_amdgcn_mfma_f32_16x16x32_bf16(a1, b0, acc[1][0], 0, 0, 0);
            acc[1][1] = __builtin_amdgcn_mfma_f32_16x16x32_bf16(a1, b1, acc[1][1], 0, 0, 0);
        }
    }
}

// ---------------------------------------------------------------------------
// fp32-input gemm core: same tile/LDS layout; staging loads fp32, converts
// bf16 in-register (RNE), ds_write_b128 into the XOR-swizzled layout.
// ---------------------------------------------------------------------------
__device__ __forceinline__ us8 cvt8(float4 a, float4 b) {
    us8 o;
    o[0] = f2b(a.x); o[1] = f2b(a.y); o[2] = f2b(a.z); o[3] = f2b(a.w);
    o[4] = f2b(b.x); o[5] = f2b(b.y); o[6] = f2b(b.z); o[7] = f2b(b.w);
    return o;
}

__device__ __forceinline__ void gemm_core_f32(
    const float* __restrict__ A, int lda, const float* __restrict__ B, int ldb,
    int r0, int c0, int K, ushort_t (*as)[64], ushort_t (*bs)[64], f4 acc[2][2])
{
    const int t = threadIdx.x;
    const int wave = t >> 6, lane = t & 63;
    const int wm = (wave & 1) * 32, wn = (wave >> 1) * 32;
    const int fm = lane & 15, fq = lane >> 4;

    const int m1 = wave * 16 + (lane >> 3);
    const int m2 = m1 + 8;
    const int g1 = ((lane & 7) ^ (m1 & 7)) * 8;
    const int g2 = ((lane & 7) ^ (m2 & 7)) * 8;
    const int cl = (lane & 7) * 8;
    const int ra0 = wm + fm, ra1 = wm + 16 + fm;
    const int rb0 = wn + fm, rb1 = wn + 16 + fm;

    for (int k0 = 0; k0 < K; k0 += 64) {
        const float4 aa0 = *(const float4*)(A + (size_t)(r0 + m1) * lda + k0 + g1);
        const float4 aa1 = *(const float4*)(A + (size_t)(r0 + m1) * lda + k0 + g1 + 4);
        const float4 ab0 = *(const float4*)(A + (size_t)(r0 + m2) * lda + k0 + g2);
        const float4 ab1 = *(const float4*)(A + (size_t)(r0 + m2) * lda + k0 + g2 + 4);
        const float4 ba0 = *(const float4*)(B + (size_t)(c0 + m1) * ldb + k0 + g1);
        const float4 ba1 = *(const float4*)(B + (size_t)(c0 + m1) * ldb + k0 + g1 + 4);
        const float4 bb0 = *(const float4*)(B + (size_t)(c0 + m2) * ldb + k0 + g2);
        const float4 bb1 = *(const float4*)(B + (size_t)(c0 + m2) * ldb + k0 + g2 + 4);
        __syncthreads();
        *(us8*)&as[m1][cl] = cvt8(aa0, aa1);
        *(us8*)&as[m2][cl] = cvt8(ab0, ab1);
        *(us8*)&bs[m1][cl] = cvt8(ba0, ba1);
        *(us8*)&bs[m2][cl] = cvt8(bb0, bb1);
        __syncthreads();
        #pragma unroll
        for (int kk = 0; kk < 2; ++kk) {
            const int cc = kk * 4 + fq;
            const s8 a0 = *(const s8*)&as[ra0][(cc ^ (ra0 & 7)) * 8];
            const s8 a1 = *(const s8*)&as[ra1][(cc ^ (ra1 & 7)) * 8];
            const s8 b0 = *(const s8*)&bs[rb0][(cc ^ (rb0 & 7)) * 8];
            const s8 b1 = *(const s8*)&bs[rb1][(cc ^ (rb1 & 7)) * 8];
            acc[0][0] = __builtin_amdgcn_mfma_f32_16x16x32_bf16(a0, b0, acc[0][0], 0, 0, 0);
            acc[0][1] = __builtin_amdgcn_mfma_f32_16x16x32_bf16(a0, b1, acc[0][1], 0, 0, 0);
            acc[1][0] = __builtin_amdgcn_mfma_f32_16x16x32_bf16(a1, b0, acc[1][0], 0, 0, 0);
            acc[1][1] = __builtin_amdgcn_mfma_f32_16x16x32_bf16(a1, b1, acc[1][1], 0, 0, 0);
        }
    }
}

// ---------------------------------------------------------------------------
// K1 union — block ranges ordered long-pole-first:
//  [0,512)      edge scan: block = (16-col chunk, layer, 1024-row half).
//               2x parallelism vs r15; per-segment cnt2 (cap 64 = +12.5σ);
//               LDS counters; block owns its cnt2 words -> no global atomics.
//  [512,1152)   gemm1 tiles (fp32 inline-convert staging):
//               [msg0|msg1|gh] = x @ [Wm0;Wm1;whh]^T + bias
//  [1152,1280)  attn_proj: acur/anb (fp32 exact)
//  [1280,1664)  wihb = bf16(wih)
// ---------------------------------------------------------------------------
#define E_SC  512
#define E_GM  1152
#define E_AP  1280
#define E_NB  1664

__global__ __launch_bounds__(256) void fused1_kernel(
    const float* __restrict__ x,
    const float* __restrict__ adj0, const float* __restrict__ adj1,
    const float* __restrict__ Wm0, const float* __restrict__ Wm1,
    const float* __restrict__ whh, const float* __restrict__ wih,
    const float* __restrict__ Wa0, const float* __restrict__ Wa1,
    const float* __restrict__ bm0, const float* __restrict__ bm1,
    const float* __restrict__ bhh,
    int* __restrict__ cnt2, int* __restrict__ ej,
    ushort_t* __restrict__ wihb,
    float* __restrict__ acur, float* __restrict__ anb,
    ushort_t* __restrict__ msgb, float* __restrict__ gh)
{
    __shared__ char smem[16448];
    const int b = blockIdx.x, t = threadIdx.x;

    if (b < E_SC) {                            // ---- edge scan (segmented) ----
        const int half = b & 1, l = (b >> 1) & 1, chunk = b >> 2;
        const int i0 = chunk * 16, j0 = half * 1024;
        const float* adj = l ? adj1 : adj0;
        int* lcnt = (int*)smem;
        if (t < 16) lcnt[t] = 0;
        __syncthreads();
        const int rowLane = t >> 2, q = t & 3;
        for (int r0r = 0; r0r < 1024; r0r += 512) {
            float4 a[8];
            #pragma unroll
            for (int it = 0; it < 8; ++it) {
                const int j = j0 + r0r + it * 64 + rowLane;
                a[it] = *(const float4*)(adj + (size_t)j * NN + i0 + q * 4);
            }
            #pragma unroll
            for (int it = 0; it < 8; ++it) {
                const int j = j0 + r0r + it * 64 + rowLane;
                const float av[4] = {a[it].x, a[it].y, a[it].z, a[it].w};
                #pragma unroll
                for (int u = 0; u < 4; ++u) {
                    if (av[u] != 0.f) {
                        const int li = q * 4 + u;
                        const int slot = atomicAdd(&lcnt[li], 1);
                        if (slot < SCAP)
                            ej[(((size_t)l * NN + i0 + li) * 2 + half) * SCAP + slot] = j;
                    }
                }
            }
        }
        __syncthreads();
        if (t < 16)
            cnt2[((size_t)l * NN + i0 + t) * 2 + half] = min(lcnt[t], SCAP);
        return;
    }
    if (b < E_GM) {                            // ---- gemm1 tile (fp32 in) ----
        ushort_t (*as)[64] = (ushort_t(*)[64])smem;
        ushort_t (*bs)[64] = (ushort_t(*)[64])(smem + 8192);
        const int wave = t >> 6, lane = t & 63;
        const int wm = (wave & 1) * 32, wn = (wave >> 1) * 32;
        const int fm = lane & 15, fq = lane >> 4;
        const int idx = b - E_SC;
        const int c0 = (idx % 20) * 64, r0 = (idx / 20) * 64;
        const float* Bsrc = (c0 < 256) ? Wm0 + (size_t)c0 * DD
                          : (c0 < 512) ? Wm1 + (size_t)(c0 - 256) * DD
                                       : whh + (size_t)(c0 - 512) * DD;
        f4 acc[2][2] = {};
        gemm_core_f32(x, DD, Bsrc, DD, r0, 0, DD, as, bs, acc);
        // C/D layout (m89-verified): col = lane&15, row = (lane>>4)*4 + reg
        #pragma unroll
        for (int ni = 0; ni < 2; ++ni) {
            const int col = c0 + wn + ni * 16 + fm;
            const float bv = (col < 256) ? bm0[col]
                           : (col < 512) ? bm1[col - 256]
                                         : bhh[col - 512];
            #pragma unroll
            for (int mi = 0; mi < 2; ++mi) {
                #pragma unroll
                for (int r = 0; r < 4; ++r) {
                    const int row = r0 + wm + mi * 16 + fq * 4 + r;
                    const float v = acc[mi][ni][r] + bv;
                    if (col < 512) msgb[(size_t)row * 512 + col] = f2b(v);
                    else           gh[(size_t)row * 768 + col - 512] = v;
                }
            }
        }
        return;
    }
    if (b < E_AP) {                            // ---- attn_proj ----
        float* sh = (float*)smem;              // [16][257]
        const int i0 = (b - E_GM) * 16;
        for (int rr = 0; rr < 16; ++rr)
            sh[rr * 257 + t] = x[(size_t)(i0 + rr) * DD + t];
        __syncthreads();
        const int r = t >> 4, idx = t & 15;
        const int l = idx >> 3, isnb = (idx >> 2) & 1, h = idx & 3;
        const float* wrow = (l ? Wa1 : Wa0) + h * (2 * DD) + isnb * DD;
        float acc = 0.f;
        for (int k = 0; k < DD; ++k) acc = fmaf(sh[r * 257 + k], wrow[k], acc);
        float* dst = isnb ? anb : acur;
        dst[((size_t)l * NN + i0 + r) * HH + h] = acc;
        return;
    }
    {                                          // ---- wih -> bf16 ----
        const int id = (b - E_AP) * 1024 + t * 4;
        const float4 v = *(const float4*)(wih + id);
        us4 o; o.x = f2b(v.x); o.y = f2b(v.y); o.z = f2b(v.z); o.w = f2b(v.w);
        *(us4*)(wihb + id) = o;
    }
}

// ---------------------------------------------------------------------------
// K2 attn: compact 2 segments, gather w per edge, edge-only softmax
// (== dense reference: exp(NEG-m) underflows to 0; isolated -> 0 via inv=0),
// aggregate bf16 msg rows -> bf16 mcat.
// ---------------------------------------------------------------------------
__global__ __launch_bounds__(256) void attn_kernel(
    const int* __restrict__ cnt2, const int* __restrict__ ej,
    const float* __restrict__ w0, const float* __restrict__ w1,
    const float* __restrict__ acur, const float* __restrict__ anb,
    const float* __restrict__ ba0, const float* __restrict__ ba1,
    const ushort_t* __restrict__ msgb, ushort_t* __restrict__ mcatb)
{
    const int i = blockIdx.x, l = blockIdx.y, t = threadIdx.x;
    __shared__ float es[HH][ECAP];
    __shared__ int ejs[ECAP];
    const size_t base = ((size_t)l * NN + i) * 2;
    const int ne0 = min(max(cnt2[base], 0), SCAP);
    const int ne1 = min(max(cnt2[base + 1], 0), SCAP);
    const int ne = ne0 + ne1;                  // <= 128 = ECAP
    const float* ba = l ? ba1 : ba0;
    const float* w  = l ? w1 : w0;

    if (t < ne) {
        const int j = (t < ne0) ? ej[base * SCAP + t]
                                : ej[(base + 1) * SCAP + (t - ne0)];
        const float wv = w[(size_t)j * NN + i];   // latency-parallel gather
        ejs[t] = j;
        const float4 av = *(const float4*)(anb + ((size_t)l * NN + j) * HH);
        const float sv[4] = {av.x, av.y, av.z, av.w};
        #pragma unroll
        for (int h = 0; h < HH; ++h) {
            float s = sv[h] + acur[((size_t)l * NN + i) * HH + h] + ba[h];
            s = (s > 0.f) ? s : 0.2f * s;           // leaky_relu(0.2)
            es[h][t] = s * wv;
        }
    }
    __syncthreads();
    {
        const int h = t >> 6, lane = t & 63;
        float s0 = (lane < ne) ? es[h][lane] : -1e30f;
        float s1 = (lane + 64 < ne) ? es[h][lane + 64] : -1e30f;
        float m = fmaxf(s0, s1);
        #pragma unroll
        for (int off = 32; off; off >>= 1) m = fmaxf(m, __shfl_xor(m, off));
        const float p0 = expf(s0 - m), p1 = expf(s1 - m);
        float sum = p0 + p1;
        #pragma unroll
        for (int off = 32; off; off >>= 1) sum += __shfl_xor(sum, off);
        const float inv = (ne > 0) ? 1.f / sum : 0.f;
        es[h][lane] = p0 * inv;
        if (lane + 64 < ECAP) es[h][lane + 64] = p1 * inv;
    }
    __syncthreads();
    const int h = t >> 6;
    const int off = l * DD + t;
    float acc = 0.f;
    int e = 0;
    for (; e + 4 <= ne; e += 4) {
        const float v0 = b2f(msgb[(size_t)ejs[e + 0] * 512 + off]);
        const float v1 = b2f(msgb[(size_t)ejs[e + 1] * 512 + off]);
        const float v2 = b2f(msgb[(size_t)ejs[e + 2] * 512 + off]);
        const float v3 = b2f(msgb[(size_t)ejs[e + 3] * 512 + off]);
        acc = fmaf(es[h][e + 0], v0, acc);
        acc = fmaf(es[h][e + 1], v1, acc);
        acc = fmaf(es[h][e + 2], v2, acc);
        acc = fmaf(es[h][e + 3], v3, acc);
    }
    for (; e < ne; ++e)
        acc = fmaf(es[h][e], b2f(msgb[(size_t)ejs[e] * 512 + off]), acc);
    mcatb[(size_t)i * (2 * DD) + off] = f2b(acc);
}

// ---------------------------------------------------------------------------
// K3: gemm2: gi[2048,768] = mcatb @ wihb^T + bih   (K=512, bf16 core)
// ---------------------------------------------------------------------------
__global__ __launch_bounds__(256) void gemm2_kernel(
    const ushort_t* __restrict__ mcatb, const ushort_t* __restrict__ wihb,
    const float* __restrict__ bih, float* __restrict__ gi)
{
    __shared__ ushort_t as[64][64];
    __shared__ ushort_t bs[64][64];
    const int t = threadIdx.x;
    const int wave = t >> 6, lane = t & 63;
    const int wm = (wave & 1) * 32, wn = (wave >> 1) * 32;
    const int fm = lane & 15, fq = lane >> 4;
    const int c0 = blockIdx.x * 64, r0 = blockIdx.y * 64;
    f4 acc[2][2] = {};
    gemm_core(mcatb, 512, wihb, 512, r0, c0, 512, as, bs, acc);
    #pragma unroll
    for (int ni = 0; ni < 2; ++ni) {
        const int col = c0 + wn + ni * 16 + fm;
        const float bv = bih[col];
        #pragma unroll
        for (int mi = 0; mi < 2; ++mi)
            #pragma unroll
            for (int r = 0; r < 4; ++r)
                gi[(size_t)(r0 + wm + mi * 16 + fq * 4 + r) * 768 + col] =
                    acc[mi][ni][r] + bv;
    }
}

// ---------------------------------------------------------------------------
// K4: GRU gates + LayerNorm.
// ---------------------------------------------------------------------------
__global__ __launch_bounds__(256) void gates_ln(
    const float* __restrict__ gi, const float* __restrict__ gh, const float* __restrict__ x,
    const float* __restrict__ lng, const float* __restrict__ lnb, float* __restrict__ out)
{
    __shared__ float rs1[4], rs2[4];
    const int t = threadIdx.x;
    const int r0 = blockIdx.x * 4;
    const float gv = lng[t], bv = lnb[t];
    float hv[4];
    #pragma unroll
    for (int r = 0; r < 4; ++r) {
        const int row = r0 + r;
        const float gir = gi[(size_t)row * 768 + t];
        const float giz = gi[(size_t)row * 768 + 256 + t];
        const float gin = gi[(size_t)row * 768 + 512 + t];
        const float ghr = gh[(size_t)row * 768 + t];
        const float ghz = gh[(size_t)row * 768 + 256 + t];
        const float ghn = gh[(size_t)row * 768 + 512 + t];
        const float rr = 1.f / (1.f + expf(-(gir + ghr)));
        const float zz = 1.f / (1.f + expf(-(giz + ghz)));
        const float nn = tanhf(gin + rr * ghn);
        hv[r] = (1.f - zz) * nn + zz * x[(size_t)row * DD + t];
    }
    const int lane = t & 63, wid = t >> 6;
    for (int r = 0; r < 4; ++r) {
        float s1 = hv[r], s2 = hv[r] * hv[r];
        #pragma unroll
        for (int off = 32; off; off >>= 1) {
            s1 += __shfl_down(s1, off);
            s2 += __shfl_down(s2, off);
        }
        if (lane == 0) { rs1[wid] = s1; rs2[wid] = s2; }
        __syncthreads();
        const float sum = rs1[0] + rs1[1] + rs1[2] + rs1[3];
        const float sq  = rs2[0] + rs2[1] + rs2[2] + rs2[3];
        const float mu  = sum * (1.f / DD);
        const float var = sq * (1.f / DD) - mu * mu;
        const float inv = rsqrtf(var + 1e-5f);
        out[(size_t)(r0 + r) * DD + t] = (hv[r] - mu) * inv * gv + bv;
        __syncthreads();
    }
}

extern "C" void kernel_launch(void* const* d_in, const int* in_sizes, int n_in,
                              void* d_out, int out_size, void* d_ws, size_t ws_size,
                              hipStream_t stream)
{
    const float* x    = (const float*)d_in[0];
    const float* adj0 = (const float*)d_in[1];
    const float* adj1 = (const float*)d_in[2];
    const float* w0   = (const float*)d_in[3];
    const float* w1   = (const float*)d_in[4];
    const float* Wm0  = (const float*)d_in[5];
    const float* bm0  = (const float*)d_in[6];
    const float* Wa0  = (const float*)d_in[7];
    const float* ba0  = (const float*)d_in[8];
    const float* Wm1  = (const float*)d_in[9];
    const float* bm1  = (const float*)d_in[10];
    const float* Wa1  = (const float*)d_in[11];
    const float* ba1  = (const float*)d_in[12];
    const float* wih  = (const float*)d_in[13];
    const float* whh  = (const float*)d_in[14];
    const float* bih  = (const float*)d_in[15];
    const float* bhh  = (const float*)d_in[16];
    const float* lng  = (const float*)d_in[17];
    const float* lnb  = (const float*)d_in[18];
    float* out = (float*)d_out;

    float* ws = (float*)d_ws;
    float* gh   = ws;            ws += (size_t)NN * 768;
    float* gi   = ws;            ws += (size_t)NN * 768;
    float* acur = ws;            ws += 2 * NN * HH;
    float* anb  = ws;            ws += 2 * NN * HH;
    int*   cnt2 = (int*)ws;      ws += 2 * NN * 2;
    int*   ej   = (int*)ws;      ws += 2 * NN * 2 * SCAP;
    ushort_t* wihb  = (ushort_t*)ws;  ws += (size_t)768 * 512 / 2;
    ushort_t* msgb  = (ushort_t*)ws;  ws += (size_t)NN * 512 / 2;
    ushort_t* mcatb = (ushort_t*)ws;  ws += (size_t)NN * 512 / 2;
    // total ~17 MB

    fused1_kernel<<<E_NB, 256, 0, stream>>>(
        x, adj0, adj1, Wm0, Wm1, whh, wih, Wa0, Wa1, bm0, bm1, bhh,
        cnt2, ej, wihb, acur, anb, msgb, gh);
    attn_kernel<<<dim3(NN, 2), 256, 0, stream>>>(
        cnt2, ej, w0, w1, acur, anb, ba0, ba1, msgb, mcatb);
    gemm2_kernel<<<dim3(12, 32), 256, 0, stream>>>(mcatb, wihb, bih, gi);
    gates_ln<<<NN / 4, 256, 0, stream>>>(gi, gh, x, lng, lnb, out);
}

// Round 17
// 169.662 us; speedup vs baseline: 1.0553x; 1.0553x over previous
//
#include <hip/hip_runtime.h>

#define NN 2048
#define DD 256
#define HH 4
#define ECAP 128

typedef unsigned short ushort_t;
typedef __attribute__((ext_vector_type(4))) unsigned short us4;
typedef __attribute__((ext_vector_type(8))) unsigned short us8;
typedef __attribute__((ext_vector_type(8))) short s8;
typedef __attribute__((ext_vector_type(4))) float f4;

__device__ __forceinline__ ushort_t f2b(float f) {   // fp32 -> bf16 bits, RNE
    unsigned int u = __float_as_uint(f);
    return (ushort_t)((u + 0x7fffu + ((u >> 16) & 1u)) >> 16);
}
__device__ __forceinline__ float b2f(ushort_t b) {
    return __uint_as_float(((unsigned int)b) << 16);
}
__device__ __forceinline__ void gl_lds16(const void* g, void* l) {
    __builtin_amdgcn_global_load_lds(
        (const __attribute__((address_space(1))) void*)g,
        (__attribute__((address_space(3))) void*)l, 16, 0, 0);
}

// ---------------------------------------------------------------------------
// bf16 gemm core (gl_lds staging, XOR-swizzled [64][64]) — used by gemm2.
// ---------------------------------------------------------------------------
__device__ __forceinline__ void gemm_core(
    const ushort_t* __restrict__ A, int lda, const ushort_t* __restrict__ B, int ldb,
    int r0, int c0, int K, ushort_t (*as)[64], ushort_t (*bs)[64], f4 acc[2][2])
{
    const int t = threadIdx.x;
    const int wave = t >> 6, lane = t & 63;
    const int wm = (wave & 1) * 32, wn = (wave >> 1) * 32;
    const int fm = lane & 15, fq = lane >> 4;

    const int m0q0 = wave * 16 + (lane >> 3);
    const int m0q1 = m0q0 + 8;
    const int cs0 = ((lane & 7) ^ (m0q0 & 7)) * 8;
    const int cs1 = ((lane & 7) ^ (m0q1 & 7)) * 8;
    const ushort_t* ga0 = A + (size_t)(r0 + m0q0) * lda + cs0;
    const ushort_t* ga1 = A + (size_t)(r0 + m0q1) * lda + cs1;
    const ushort_t* gb0 = B + (size_t)(c0 + m0q0) * ldb + cs0;
    const ushort_t* gb1 = B + (size_t)(c0 + m0q1) * ldb + cs1;
    ushort_t* la0 = &as[wave * 16][0];
    ushort_t* la1 = &as[wave * 16 + 8][0];
    ushort_t* lb0 = &bs[wave * 16][0];
    ushort_t* lb1 = &bs[wave * 16 + 8][0];
    const int ra0 = wm + fm, ra1 = wm + 16 + fm;
    const int rb0 = wn + fm, rb1 = wn + 16 + fm;

    for (int k0 = 0; k0 < K; k0 += 64) {
        __syncthreads();
        gl_lds16(ga0 + k0, la0);
        gl_lds16(ga1 + k0, la1);
        gl_lds16(gb0 + k0, lb0);
        gl_lds16(gb1 + k0, lb1);
        __syncthreads();
        #pragma unroll
        for (int kk = 0; kk < 2; ++kk) {
            const int cc = kk * 4 + fq;
            const s8 a0 = *(const s8*)&as[ra0][(cc ^ (ra0 & 7)) * 8];
            const s8 a1 = *(const s8*)&as[ra1][(cc ^ (ra1 & 7)) * 8];
            const s8 b0 = *(const s8*)&bs[rb0][(cc ^ (rb0 & 7)) * 8];
            const s8 b1 = *(const s8*)&bs[rb1][(cc ^ (rb1 & 7)) * 8];
            acc[0][0] = __builtin_amdgcn_mfma_f32_16x16x32_bf16(a0, b0, acc[0][0], 0, 0, 0);
            acc[0][1] = __builtin_amdgcn_mfma_f32_16x16x32_bf16(a0, b1, acc[0][1], 0, 0, 0);
            acc[1][0] = __builtin_amdgcn_mfma_f32_16x16x32_bf16(a1, b0, acc[1][0], 0, 0, 0);
            acc[1][1] = __builtin_amdgcn_mfma_f32_16x16x32_bf16(a1, b1, acc[1][1], 0, 0, 0);
        }
    }
}

// ---------------------------------------------------------------------------
// fp32-input gemm core: identical tile geometry/LDS layout, but staging loads
// fp32, converts to bf16 in-register (RNE), and ds_write_b128s into the same
// XOR-swizzled layout. Global loads issue before the barrier -> overlap
// previous k-step's MFMA.
// ---------------------------------------------------------------------------
__device__ __forceinline__ us8 cvt8(float4 a, float4 b) {
    us8 o;
    o[0] = f2b(a.x); o[1] = f2b(a.y); o[2] = f2b(a.z); o[3] = f2b(a.w);
    o[4] = f2b(b.x); o[5] = f2b(b.y); o[6] = f2b(b.z); o[7] = f2b(b.w);
    return o;
}

__device__ __forceinline__ void gemm_core_f32(
    const float* __restrict__ A, int lda, const float* __restrict__ B, int ldb,
    int r0, int c0, int K, ushort_t (*as)[64], ushort_t (*bs)[64], f4 acc[2][2])
{
    const int t = threadIdx.x;
    const int wave = t >> 6, lane = t & 63;
    const int wm = (wave & 1) * 32, wn = (wave >> 1) * 32;
    const int fm = lane & 15, fq = lane >> 4;

    const int m1 = wave * 16 + (lane >> 3);
    const int m2 = m1 + 8;
    const int g1 = ((lane & 7) ^ (m1 & 7)) * 8;   // global elem offset (swizzled)
    const int g2 = ((lane & 7) ^ (m2 & 7)) * 8;
    const int cl = (lane & 7) * 8;                // LDS chunk offset
    const int ra0 = wm + fm, ra1 = wm + 16 + fm;
    const int rb0 = wn + fm, rb1 = wn + 16 + fm;

    for (int k0 = 0; k0 < K; k0 += 64) {
        const float4 aa0 = *(const float4*)(A + (size_t)(r0 + m1) * lda + k0 + g1);
        const float4 aa1 = *(const float4*)(A + (size_t)(r0 + m1) * lda + k0 + g1 + 4);
        const float4 ab0 = *(const float4*)(A + (size_t)(r0 + m2) * lda + k0 + g2);
        const float4 ab1 = *(const float4*)(A + (size_t)(r0 + m2) * lda + k0 + g2 + 4);
        const float4 ba0 = *(const float4*)(B + (size_t)(c0 + m1) * ldb + k0 + g1);
        const float4 ba1 = *(const float4*)(B + (size_t)(c0 + m1) * ldb + k0 + g1 + 4);
        const float4 bb0 = *(const float4*)(B + (size_t)(c0 + m2) * ldb + k0 + g2);
        const float4 bb1 = *(const float4*)(B + (size_t)(c0 + m2) * ldb + k0 + g2 + 4);
        __syncthreads();                       // prev compute done, LDS free
        *(us8*)&as[m1][cl] = cvt8(aa0, aa1);
        *(us8*)&as[m2][cl] = cvt8(ab0, ab1);
        *(us8*)&bs[m1][cl] = cvt8(ba0, ba1);
        *(us8*)&bs[m2][cl] = cvt8(bb0, bb1);
        __syncthreads();
        #pragma unroll
        for (int kk = 0; kk < 2; ++kk) {
            const int cc = kk * 4 + fq;
            const s8 a0 = *(const s8*)&as[ra0][(cc ^ (ra0 & 7)) * 8];
            const s8 a1 = *(const s8*)&as[ra1][(cc ^ (ra1 & 7)) * 8];
            const s8 b0 = *(const s8*)&bs[rb0][(cc ^ (rb0 & 7)) * 8];
            const s8 b1 = *(const s8*)&bs[rb1][(cc ^ (rb1 & 7)) * 8];
            acc[0][0] = __builtin_amdgcn_mfma_f32_16x16x32_bf16(a0, b0, acc[0][0], 0, 0, 0);
            acc[0][1] = __builtin_amdgcn_mfma_f32_16x16x32_bf16(a0, b1, acc[0][1], 0, 0, 0);
            acc[1][0] = __builtin_amdgcn_mfma_f32_16x16x32_bf16(a1, b0, acc[1][0], 0, 0, 0);
            acc[1][1] = __builtin_amdgcn_mfma_f32_16x16x32_bf16(a1, b1, acc[1][1], 0, 0, 0);
        }
    }
}

// ---------------------------------------------------------------------------
// K1 union (everything that reads only inputs):
//  [0,256)      edge scan (adj only; LDS counters; block owns cnt words)
//  [256,384)    attn_proj: acur/anb (fp32 exact)
//  [384,768)    wihb = bf16(wih)  (gemm2's B operand)
//  [768,1408)   gemm1 tiles, fp32 inline-convert staging:
//               [msg0|msg1|gh] = x @ [Wm0;Wm1;whh]^T + bias.
// r16 lesson: this ordering (scan early but NOT crowding out the gemm tiles,
// single-segment scan) is the best measured config — 168.7 µs.
// ---------------------------------------------------------------------------
#define E_SC  256
#define E_AP  384
#define E_WI  768
#define E_NB  1408

__global__ __launch_bounds__(256) void fused1_kernel(
    const float* __restrict__ x,
    const float* __restrict__ adj0, const float* __restrict__ adj1,
    const float* __restrict__ Wm0, const float* __restrict__ Wm1,
    const float* __restrict__ whh, const float* __restrict__ wih,
    const float* __restrict__ Wa0, const float* __restrict__ Wa1,
    const float* __restrict__ bm0, const float* __restrict__ bm1,
    const float* __restrict__ bhh,
    int* __restrict__ cnt, int* __restrict__ ej,
    ushort_t* __restrict__ wihb,
    float* __restrict__ acur, float* __restrict__ anb,
    ushort_t* __restrict__ msgb, float* __restrict__ gh)
{
    __shared__ char smem[16448];               // max(gemm 16384, attn_proj 16448)
    const int b = blockIdx.x, t = threadIdx.x;

    if (b < E_SC) {                            // ---- adj-only edge scan ----
        const int l = b & 1, chunk = b >> 1;
        const int i0 = chunk * 16;
        const float* adj = l ? adj1 : adj0;
        int* lcnt = (int*)smem;
        if (t < 16) lcnt[t] = 0;
        __syncthreads();
        const int rowLane = t >> 2, q = t & 3;
        for (int r0r = 0; r0r < NN; r0r += 512) {
            float4 a[8];
            #pragma unroll
            for (int it = 0; it < 8; ++it) {
                const int j = r0r + it * 64 + rowLane;
                a[it] = *(const float4*)(adj + (size_t)j * NN + i0 + q * 4);
            }
            #pragma unroll
            for (int it = 0; it < 8; ++it) {
                const int j = r0r + it * 64 + rowLane;
                const float av[4] = {a[it].x, a[it].y, a[it].z, a[it].w};
                #pragma unroll
                for (int u = 0; u < 4; ++u) {
                    if (av[u] != 0.f) {
                        const int li = q * 4 + u;
                        const int slot = atomicAdd(&lcnt[li], 1);
                        if (slot < ECAP)
                            ej[((size_t)l * NN + i0 + li) * ECAP + slot] = j;
                    }
                }
            }
        }
        __syncthreads();
        if (t < 16) cnt[l * NN + i0 + t] = min(lcnt[t], ECAP);
        return;
    }
    if (b < E_AP) {                            // ---- attn_proj ----
        float* sh = (float*)smem;              // [16][257]
        const int i0 = (b - E_SC) * 16;
        for (int rr = 0; rr < 16; ++rr)
            sh[rr * 257 + t] = x[(size_t)(i0 + rr) * DD + t];
        __syncthreads();
        const int r = t >> 4, idx = t & 15;
        const int l = idx >> 3, isnb = (idx >> 2) & 1, h = idx & 3;
        const float* wrow = (l ? Wa1 : Wa0) + h * (2 * DD) + isnb * DD;
        float acc = 0.f;
        for (int k = 0; k < DD; ++k) acc = fmaf(sh[r * 257 + k], wrow[k], acc);
        float* dst = isnb ? anb : acur;
        dst[((size_t)l * NN + i0 + r) * HH + h] = acc;
        return;
    }
    if (b < E_WI) {                            // ---- wih -> bf16 ----
        const int id = (b - E_AP) * 1024 + t * 4;
        const float4 v = *(const float4*)(wih + id);
        us4 o; o.x = f2b(v.x); o.y = f2b(v.y); o.z = f2b(v.z); o.w = f2b(v.w);
        *(us4*)(wihb + id) = o;
        return;
    }
    {                                          // ---- gemm1 tile (fp32 in) ----
        ushort_t (*as)[64] = (ushort_t(*)[64])smem;
        ushort_t (*bs)[64] = (ushort_t(*)[64])(smem + 8192);
        const int wave = t >> 6, lane = t & 63;
        const int wm = (wave & 1) * 32, wn = (wave >> 1) * 32;
        const int fm = lane & 15, fq = lane >> 4;
        const int idx = b - E_WI;
        const int c0 = (idx % 20) * 64, r0 = (idx / 20) * 64;
        const float* Bsrc = (c0 < 256) ? Wm0 + (size_t)c0 * DD
                          : (c0 < 512) ? Wm1 + (size_t)(c0 - 256) * DD
                                       : whh + (size_t)(c0 - 512) * DD;
        f4 acc[2][2] = {};
        gemm_core_f32(x, DD, Bsrc, DD, r0, 0, DD, as, bs, acc);
        // C/D layout (m89-verified): col = lane&15, row = (lane>>4)*4 + reg
        #pragma unroll
        for (int ni = 0; ni < 2; ++ni) {
            const int col = c0 + wn + ni * 16 + fm;
            const float bv = (col < 256) ? bm0[col]
                           : (col < 512) ? bm1[col - 256]
                                         : bhh[col - 512];
            #pragma unroll
            for (int mi = 0; mi < 2; ++mi) {
                #pragma unroll
                for (int r = 0; r < 4; ++r) {
                    const int row = r0 + wm + mi * 16 + fq * 4 + r;
                    const float v = acc[mi][ni][r] + bv;
                    if (col < 512) msgb[(size_t)row * 512 + col] = f2b(v);
                    else           gh[(size_t)row * 768 + col - 512] = v;
                }
            }
        }
    }
}

// ---------------------------------------------------------------------------
// K2 attn: gather w per edge, edge-only softmax (== dense reference:
// exp(NEG-m) underflows to 0; isolated -> 0 via inv=0), aggregate bf16 msg.
// ---------------------------------------------------------------------------
__global__ __launch_bounds__(256) void attn_kernel(
    const int* __restrict__ cnt, const int* __restrict__ ej,
    const float* __restrict__ w0, const float* __restrict__ w1,
    const float* __restrict__ acur, const float* __restrict__ anb,
    const float* __restrict__ ba0, const float* __restrict__ ba1,
    const ushort_t* __restrict__ msgb, ushort_t* __restrict__ mcatb)
{
    const int i = blockIdx.x, l = blockIdx.y, t = threadIdx.x;
    __shared__ float es[HH][ECAP];
    __shared__ int ejs[ECAP];
    const int ne = min(max(cnt[l * NN + i], 0), ECAP);
    const float* ba = l ? ba1 : ba0;
    const float* w  = l ? w1 : w0;
    const size_t ebase = ((size_t)l * NN + i) * ECAP;

    if (t < ne) {
        const int j = ej[ebase + t];
        const float wv = w[(size_t)j * NN + i];   // latency-parallel gather
        ejs[t] = j;
        const float4 av = *(const float4*)(anb + ((size_t)l * NN + j) * HH);
        const float sv[4] = {av.x, av.y, av.z, av.w};
        #pragma unroll
        for (int h = 0; h < HH; ++h) {
            float s = sv[h] + acur[((size_t)l * NN + i) * HH + h] + ba[h];
            s = (s > 0.f) ? s : 0.2f * s;           // leaky_relu(0.2)
            es[h][t] = s * wv;
        }
    }
    __syncthreads();
    {
        const int h = t >> 6, lane = t & 63;
        float s0 = (lane < ne) ? es[h][lane] : -1e30f;
        float s1 = (lane + 64 < ne) ? es[h][lane + 64] : -1e30f;
        float m = fmaxf(s0, s1);
        #pragma unroll
        for (int off = 32; off; off >>= 1) m = fmaxf(m, __shfl_xor(m, off));
        const float p0 = expf(s0 - m), p1 = expf(s1 - m);
        float sum = p0 + p1;
        #pragma unroll
        for (int off = 32; off; off >>= 1) sum += __shfl_xor(sum, off);
        const float inv = (ne > 0) ? 1.f / sum : 0.f;
        es[h][lane] = p0 * inv;
        if (lane + 64 < ECAP) es[h][lane + 64] = p1 * inv;
    }
    __syncthreads();
    const int h = t >> 6;
    const int off = l * DD + t;
    float acc = 0.f;
    int e = 0;
    for (; e + 4 <= ne; e += 4) {
        const float v0 = b2f(msgb[(size_t)ejs[e + 0] * 512 + off]);
        const float v1 = b2f(msgb[(size_t)ejs[e + 1] * 512 + off]);
        const float v2 = b2f(msgb[(size_t)ejs[e + 2] * 512 + off]);
        const float v3 = b2f(msgb[(size_t)ejs[e + 3] * 512 + off]);
        acc = fmaf(es[h][e + 0], v0, acc);
        acc = fmaf(es[h][e + 1], v1, acc);
        acc = fmaf(es[h][e + 2], v2, acc);
        acc = fmaf(es[h][e + 3], v3, acc);
    }
    for (; e < ne; ++e)
        acc = fmaf(es[h][e], b2f(msgb[(size_t)ejs[e] * 512 + off]), acc);
    mcatb[(size_t)i * (2 * DD) + off] = f2b(acc);
}

// ---------------------------------------------------------------------------
// K3: gemm2: gi[2048,768] = mcatb @ wihb^T + bih   (K=512, bf16 core)
// ---------------------------------------------------------------------------
__global__ __launch_bounds__(256) void gemm2_kernel(
    const ushort_t* __restrict__ mcatb, const ushort_t* __restrict__ wihb,
    const float* __restrict__ bih, float* __restrict__ gi)
{
    __shared__ ushort_t as[64][64];
    __shared__ ushort_t bs[64][64];
    const int t = threadIdx.x;
    const int wave = t >> 6, lane = t & 63;
    const int wm = (wave & 1) * 32, wn = (wave >> 1) * 32;
    const int fm = lane & 15, fq = lane >> 4;
    const int c0 = blockIdx.x * 64, r0 = blockIdx.y * 64;
    f4 acc[2][2] = {};
    gemm_core(mcatb, 512, wihb, 512, r0, c0, 512, as, bs, acc);
    #pragma unroll
    for (int ni = 0; ni < 2; ++ni) {
        const int col = c0 + wn + ni * 16 + fm;
        const float bv = bih[col];
        #pragma unroll
        for (int mi = 0; mi < 2; ++mi)
            #pragma unroll
            for (int r = 0; r < 4; ++r)
                gi[(size_t)(r0 + wm + mi * 16 + fq * 4 + r) * 768 + col] =
                    acc[mi][ni][r] + bv;
    }
}

// ---------------------------------------------------------------------------
// K4: GRU gates + LayerNorm.
// ---------------------------------------------------------------------------
__global__ __launch_bounds__(256) void gates_ln(
    const float* __restrict__ gi, const float* __restrict__ gh, const float* __restrict__ x,
    const float* __restrict__ lng, const float* __restrict__ lnb, float* __restrict__ out)
{
    __shared__ float rs1[4], rs2[4];
    const int t = threadIdx.x;
    const int r0 = blockIdx.x * 4;
    const float gv = lng[t], bv = lnb[t];
    float hv[4];
    #pragma unroll
    for (int r = 0; r < 4; ++r) {
        const int row = r0 + r;
        const float gir = gi[(size_t)row * 768 + t];
        const float giz = gi[(size_t)row * 768 + 256 + t];
        const float gin = gi[(size_t)row * 768 + 512 + t];
        const float ghr = gh[(size_t)row * 768 + t];
        const float ghz = gh[(size_t)row * 768 + 256 + t];
        const float ghn = gh[(size_t)row * 768 + 512 + t];
        const float rr = 1.f / (1.f + expf(-(gir + ghr)));
        const float zz = 1.f / (1.f + expf(-(giz + ghz)));
        const float nn = tanhf(gin + rr * ghn);
        hv[r] = (1.f - zz) * nn + zz * x[(size_t)row * DD + t];
    }
    const int lane = t & 63, wid = t >> 6;
    for (int r = 0; r < 4; ++r) {
        float s1 = hv[r], s2 = hv[r] * hv[r];
        #pragma unroll
        for (int off = 32; off; off >>= 1) {
            s1 += __shfl_down(s1, off);
            s2 += __shfl_down(s2, off);
        }
        if (lane == 0) { rs1[wid] = s1; rs2[wid] = s2; }
        __syncthreads();
        const float sum = rs1[0] + rs1[1] + rs1[2] + rs1[3];
        const float sq  = rs2[0] + rs2[1] + rs2[2] + rs2[3];
        const float mu  = sum * (1.f / DD);
        const float var = sq * (1.f / DD) - mu * mu;
        const float inv = rsqrtf(var + 1e-5f);
        out[(size_t)(r0 + r) * DD + t] = (hv[r] - mu) * inv * gv + bv;
        __syncthreads();
    }
}

extern "C" void kernel_launch(void* const* d_in, const int* in_sizes, int n_in,
                              void* d_out, int out_size, void* d_ws, size_t ws_size,
                              hipStream_t stream)
{
    const float* x    = (const float*)d_in[0];
    const float* adj0 = (const float*)d_in[1];
    const float* adj1 = (const float*)d_in[2];
    const float* w0   = (const float*)d_in[3];
    const float* w1   = (const float*)d_in[4];
    const float* Wm0  = (const float*)d_in[5];
    const float* bm0  = (const float*)d_in[6];
    const float* Wa0  = (const float*)d_in[7];
    const float* ba0  = (const float*)d_in[8];
    const float* Wm1  = (const float*)d_in[9];
    const float* bm1  = (const float*)d_in[10];
    const float* Wa1  = (const float*)d_in[11];
    const float* ba1  = (const float*)d_in[12];
    const float* wih  = (const float*)d_in[13];
    const float* whh  = (const float*)d_in[14];
    const float* bih  = (const float*)d_in[15];
    const float* bhh  = (const float*)d_in[16];
    const float* lng  = (const float*)d_in[17];
    const float* lnb  = (const float*)d_in[18];
    float* out = (float*)d_out;

    float* ws = (float*)d_ws;
    float* gh   = ws;            ws += (size_t)NN * 768;
    float* gi   = ws;            ws += (size_t)NN * 768;
    float* acur = ws;            ws += 2 * NN * HH;
    float* anb  = ws;            ws += 2 * NN * HH;
    int*   cnt  = (int*)ws;      ws += 2 * NN;
    int*   ej   = (int*)ws;      ws += 2 * NN * ECAP;
    ushort_t* wihb  = (ushort_t*)ws;  ws += (size_t)768 * 512 / 2;
    ushort_t* msgb  = (ushort_t*)ws;  ws += (size_t)NN * 512 / 2;
    ushort_t* mcatb = (ushort_t*)ws;  ws += (size_t)NN * 512 / 2;
    // total ~17 MB

    fused1_kernel<<<E_NB, 256, 0, stream>>>(
        x, adj0, adj1, Wm0, Wm1, whh, wih, Wa0, Wa1, bm0, bm1, bhh,
        cnt, ej, wihb, acur, anb, msgb, gh);
    attn_kernel<<<dim3(NN, 2), 256, 0, stream>>>(
        cnt, ej, w0, w1, acur, anb, ba0, ba1, msgb, mcatb);
    gemm2_kernel<<<dim3(12, 32), 256, 0, stream>>>(mcatb, wihb, bih, gi);
    gates_ln<<<NN / 4, 256, 0, stream>>>(gi, gh, x, lng, lnb, out);
}